// Round 1
// baseline (645.536 us; speedup 1.0000x reference)
//
#include <hip/hip_runtime.h>

// Problem constants (B=2, L=512, D_NODE=256, D_PAIR=128)
#define BB   2
#define LL   512
#define DN   256
#define DP   128
#define TJ   64            // j-rows per chunk in K2 (4 waves x 16 rows)
#define LDSW 136           // padded LDS row stride in bf16 elems (+8 -> +16B)

using bf16x8 = __attribute__((ext_vector_type(8))) short;   // 8 bf16 = 4 VGPRs
using f32x4  = __attribute__((ext_vector_type(4))) float;   // MFMA accumulator

__device__ inline unsigned short f2bf(float f) {
    unsigned int u = __float_as_uint(f);
    u += 0x7FFFu + ((u >> 16) & 1u);       // round-to-nearest-even
    return (unsigned short)(u >> 16);
}

// -------- K1: x = layernorm(single); a = x@Wa.T+ba (fp32); b = x@Wb.T+bb (bf16)
__global__ __launch_bounds__(256) void pu_ln_ab(
    const float* __restrict__ single, const float* __restrict__ norm_g,
    const float* __restrict__ norm_b, const float* __restrict__ Wa,
    const float* __restrict__ ba, const float* __restrict__ Wb,
    const float* __restrict__ bbias, float* __restrict__ abuf,
    unsigned short* __restrict__ bbuf)
{
    __shared__ __attribute__((aligned(16))) float xs[DN];
    __shared__ float red[8];
    const int row = blockIdx.x;           // 0..B*L-1
    const int tid = threadIdx.x;          // 0..255

    float v = single[row * DN + tid];
    float s1 = v, s2 = v * v;
    #pragma unroll
    for (int m = 32; m; m >>= 1) {        // wave64 butterfly
        s1 += __shfl_xor(s1, m);
        s2 += __shfl_xor(s2, m);
    }
    const int w = tid >> 6;
    if ((tid & 63) == 0) { red[w] = s1; red[4 + w] = s2; }
    __syncthreads();
    s1 = red[0] + red[1] + red[2] + red[3];
    s2 = red[4] + red[5] + red[6] + red[7];
    const float mu  = s1 * (1.0f / DN);
    const float var = s2 * (1.0f / DN) - mu * mu;
    const float rs  = rsqrtf(var + 1e-5f);
    xs[tid] = (v - mu) * rs * norm_g[tid] + norm_b[tid];
    __syncthreads();

    const int half = tid >> 7, p = tid & 127;
    const float4* W4 = (const float4*)((half ? Wb : Wa) + p * DN);
    const float4* x4 = (const float4*)xs;
    float acc = 0.f;
    #pragma unroll 8
    for (int d = 0; d < DN / 4; d++) {
        float4 wv = W4[d], xv = x4[d];
        acc += wv.x * xv.x + wv.y * xv.y + wv.z * xv.z + wv.w * xv.w;
    }
    acc += (half ? bbias[p] : ba[p]);
    if (half == 0) abuf[row * DP + p] = acc;
    else           bbuf[row * DP + p] = f2bf(acc);
}

// -------- K2: upd = (a_i * b_j) @ Wo.T + bo; out = layernorm(pair + upd)
// Persistent-i block: one block per (b,i). Stage sW ONCE, one barrier,
// then stream 8 chunks of 64 j-rows with zero further barriers.
// A-fragments come straight from L2-resident bbuf (no sB in LDS).
__global__ __launch_bounds__(256, 4) void pu_outer_ln(
    const float* __restrict__ pr, const float* __restrict__ Wo,
    const float* __restrict__ bo, const float* __restrict__ png,
    const float* __restrict__ pnb, const float* __restrict__ abuf,
    const unsigned short* __restrict__ bbuf, float* __restrict__ out)
{
    __shared__ __attribute__((aligned(16))) unsigned short sW[DP * LDSW]; // W_i[p][d] bf16, 34.8 KB

    const int i    = blockIdx.x;          // 0..511
    const int bz   = blockIdx.y;          // 0..1
    const int tid  = threadIdx.x;
    const int lane = tid & 63;
    const int w    = tid >> 6;            // wave -> j rows [w*16, w*16+16) of each chunk
    const int m    = lane & 15;           // col (p) within 16-tile / A row (j)
    const int q    = lane >> 4;           // quad

    // ---- epilogue constants for this lane's p = t*16+m (L1-resident loads)
    float bo_r[8], g_r[8], pb_r[8];
    #pragma unroll
    for (int t = 0; t < 8; t++) {
        bo_r[t] = bo[t * 16 + m];
        g_r[t]  = png[t * 16 + m];
        pb_r[t] = pnb[t * 16 + m];
    }

    const size_t ibase = (((size_t)bz * LL + i) * LL) * DP;   // pair/out base for this (b,i)
    const unsigned short* bbb = bbuf + (size_t)bz * LL * DP;

    // ---- prologue prefetch: chunk 0 pair tile + A-fragments (overlap with sW staging)
    float pv[4][8];
    #pragma unroll
    for (int r = 0; r < 4; r++) {
        const size_t rowoff = ibase + (size_t)(w * 16 + q * 4 + r) * DP + m;
        #pragma unroll
        for (int t = 0; t < 8; t++) pv[r][t] = pr[rowoff + t * 16];
    }
    bf16x8 afr[4];
    {
        const unsigned short* brow = bbb + (size_t)(w * 16 + m) * DP + q * 8;
        #pragma unroll
        for (int s = 0; s < 4; s++) afr[s] = *(const bf16x8*)(brow + s * 32);
    }

    // ---- stage W_i = bf16(a[i,d] * Wo[p,d]) ONCE: 2048 vec8, 8 per thread
    const float* arow = abuf + ((size_t)bz * LL + i) * DP;
    #pragma unroll
    for (int e = 0; e < 8; e++) {
        const int v  = tid + e * 256;     // 0..2047
        const int pw = v >> 4;            // p row
        const int d0 = (v & 15) * 8;
        const float4* w4 = (const float4*)(Wo + pw * DP + d0);
        const float4* a4 = (const float4*)(arow + d0);
        float4 wa = w4[0], wb = w4[1], aa = a4[0], ab = a4[1];
        uint4 pk;
        pk.x = (unsigned)f2bf(wa.x * aa.x) | ((unsigned)f2bf(wa.y * aa.y) << 16);
        pk.y = (unsigned)f2bf(wa.z * aa.z) | ((unsigned)f2bf(wa.w * aa.w) << 16);
        pk.z = (unsigned)f2bf(wb.x * ab.x) | ((unsigned)f2bf(wb.y * ab.y) << 16);
        pk.w = (unsigned)f2bf(wb.z * ab.z) | ((unsigned)f2bf(wb.w * ab.w) << 16);
        *(uint4*)&sW[pw * LDSW + d0] = pk;
    }
    __syncthreads();                      // the ONLY barrier in this kernel

    const unsigned short* Bbase = sW + m * LDSW + q * 8;

    for (int jc = 0; jc < 8; jc++) {
        const int j0 = jc * TJ;

        // ---- MFMA: C[16j x 128p] per wave, K=128 in 4 steps of 32
        f32x4 acc[8];
        #pragma unroll
        for (int t = 0; t < 8; t++) { f32x4 z = {0.f, 0.f, 0.f, 0.f}; acc[t] = z; }

        #pragma unroll
        for (int s = 0; s < 4; s++) {
            bf16x8 af = afr[s];
            #pragma unroll
            for (int t = 0; t < 8; t++) {
                bf16x8 bfv = *(const bf16x8*)(Bbase + t * 16 * LDSW + s * 32);
                acc[t] = __builtin_amdgcn_mfma_f32_16x16x32_bf16(af, bfv, acc[t], 0, 0, 0);
            }
        }

        // ---- prefetch next chunk's A-fragments (afr free after MFMA loop)
        if (jc < 7) {
            const unsigned short* brow =
                bbb + (size_t)(j0 + TJ + w * 16 + m) * DP + q * 8;
            #pragma unroll
            for (int s = 0; s < 4; s++) afr[s] = *(const bf16x8*)(brow + s * 32);
        }

        // ---- epilogue: +pair +bo, row layernorm over p (16-lane reduce), store
        const size_t obase = ibase + (size_t)(j0 + w * 16) * DP;
        #pragma unroll
        for (int r = 0; r < 4; r++) {
            const size_t rowoff = obase + (size_t)(q * 4 + r) * DP + m;
            float v[8], s1 = 0.f, s2 = 0.f;
            #pragma unroll
            for (int t = 0; t < 8; t++) {
                v[t] = pv[r][t] + acc[t][r] + bo_r[t];
                s1 += v[t];
                s2 += v[t] * v[t];
            }
            s1 += __shfl_xor(s1, 1); s2 += __shfl_xor(s2, 1);
            s1 += __shfl_xor(s1, 2); s2 += __shfl_xor(s2, 2);
            s1 += __shfl_xor(s1, 4); s2 += __shfl_xor(s2, 4);
            s1 += __shfl_xor(s1, 8); s2 += __shfl_xor(s2, 8);
            const float mu  = s1 * (1.0f / DP);
            const float var = s2 * (1.0f / DP) - mu * mu;
            const float rs  = rsqrtf(var + 1e-5f);
            #pragma unroll
            for (int t = 0; t < 8; t++)
                out[rowoff + t * 16] = (v[t] - mu) * rs * g_r[t] + pb_r[t];
        }

        // ---- prefetch next chunk's pair tile (pv free after epilogue)
        if (jc < 7) {
            const size_t nb = ibase + (size_t)(j0 + TJ + w * 16) * DP;
            #pragma unroll
            for (int r = 0; r < 4; r++) {
                const size_t rowoff = nb + (size_t)(q * 4 + r) * DP + m;
                #pragma unroll
                for (int t = 0; t < 8; t++) pv[r][t] = pr[rowoff + t * 16];
            }
        }
    }
}

extern "C" void kernel_launch(void* const* d_in, const int* in_sizes, int n_in,
                              void* d_out, int out_size, void* d_ws, size_t ws_size,
                              hipStream_t stream) {
    const float* single = (const float*)d_in[0];
    const float* pair   = (const float*)d_in[1];
    const float* norm_g = (const float*)d_in[2];
    const float* norm_b = (const float*)d_in[3];
    const float* Wa     = (const float*)d_in[4];
    const float* ba     = (const float*)d_in[5];
    const float* Wb     = (const float*)d_in[6];
    const float* bb     = (const float*)d_in[7];
    const float* Wo     = (const float*)d_in[8];
    const float* bo     = (const float*)d_in[9];
    const float* png    = (const float*)d_in[10];
    const float* pnb    = (const float*)d_in[11];
    float* out = (float*)d_out;

    float* abuf = (float*)d_ws;                                        // 512 KB fp32
    unsigned short* bbuf =
        (unsigned short*)((char*)d_ws + (size_t)BB * LL * DP * sizeof(float)); // 256 KB bf16

    pu_ln_ab<<<dim3(BB * LL), dim3(256), 0, stream>>>(
        single, norm_g, norm_b, Wa, ba, Wb, bb, abuf, bbuf);

    pu_outer_ln<<<dim3(LL, BB), dim3(256), 0, stream>>>(
        pair, Wo, bo, png, pnb, abuf, bbuf, out);
}

// Round 4
// 490.142 us; speedup vs baseline: 1.3170x; 1.3170x over previous
//
#include <hip/hip_runtime.h>

// Problem constants (B=2, L=512, D_NODE=256, D_PAIR=128)
#define BB   2
#define LL   512
#define DN   256
#define DP   128
#define TJ   64            // j-rows per block in K2 (4 waves x 16 rows)
#define LDSW 136           // padded LDS row stride in bf16 elems (+8 -> +16B)

using bf16x8 = __attribute__((ext_vector_type(8))) short;   // 8 bf16 = 4 VGPRs
using f32x4  = __attribute__((ext_vector_type(4))) float;   // MFMA accumulator

__device__ inline unsigned short f2bf(float f) {
    unsigned int u = __float_as_uint(f);
    u += 0x7FFFu + ((u >> 16) & 1u);       // round-to-nearest-even
    return (unsigned short)(u >> 16);
}

// -------- K1: x = layernorm(single); a = x@Wa.T+ba (fp32); b = bf16(x@Wb.T+bb);
//          plus one-time Wo fp32 -> bf16 convert (32 KB, blocks 0..15)
__global__ __launch_bounds__(256) void pu_ln_ab(
    const float* __restrict__ single, const float* __restrict__ norm_g,
    const float* __restrict__ norm_b, const float* __restrict__ Wa,
    const float* __restrict__ ba, const float* __restrict__ Wb,
    const float* __restrict__ bbias, const float* __restrict__ Wo,
    float* __restrict__ abuf, unsigned short* __restrict__ bbuf,
    unsigned short* __restrict__ wo)
{
    __shared__ __attribute__((aligned(16))) float xs[DN];
    __shared__ float red[8];
    const int row = blockIdx.x;           // 0..B*L-1
    const int tid = threadIdx.x;          // 0..255

    // one-time Wo bf16 pack: 16 blocks x 256 threads x 4 elems = 16384
    if (wo != nullptr && row < 16) {
        const int g0 = (row * 256 + tid) * 4;
        const float4 wv = *(const float4*)(Wo + g0);
        uint2 pk;
        pk.x = (unsigned)f2bf(wv.x) | ((unsigned)f2bf(wv.y) << 16);
        pk.y = (unsigned)f2bf(wv.z) | ((unsigned)f2bf(wv.w) << 16);
        *(uint2*)&wo[g0] = pk;
    }

    float v = single[row * DN + tid];
    float s1 = v, s2 = v * v;
    #pragma unroll
    for (int m = 32; m; m >>= 1) {        // wave64 butterfly
        s1 += __shfl_xor(s1, m);
        s2 += __shfl_xor(s2, m);
    }
    const int w = tid >> 6;
    if ((tid & 63) == 0) { red[w] = s1; red[4 + w] = s2; }
    __syncthreads();
    s1 = red[0] + red[1] + red[2] + red[3];
    s2 = red[4] + red[5] + red[6] + red[7];
    const float mu  = s1 * (1.0f / DN);
    const float var = s2 * (1.0f / DN) - mu * mu;
    const float rs  = rsqrtf(var + 1e-5f);
    xs[tid] = (v - mu) * rs * norm_g[tid] + norm_b[tid];
    __syncthreads();

    const int half = tid >> 7, p = tid & 127;
    const float4* W4 = (const float4*)((half ? Wb : Wa) + p * DN);
    const float4* x4 = (const float4*)xs;
    float acc = 0.f;
    #pragma unroll 8
    for (int d = 0; d < DN / 4; d++) {
        float4 wv = W4[d], xv = x4[d];
        acc += wv.x * xv.x + wv.y * xv.y + wv.z * xv.z + wv.w * xv.w;
    }
    acc += (half ? bbias[p] : ba[p]);
    if (half == 0) abuf[row * DP + p] = acc;
    else           bbuf[row * DP + p] = f2bf(acc);
}

// -------- K2 (new path): upd[j,p] = sum_d bf16(a_i[d]*b_j[d]) * bf16(Wo[p,d]);
// out = layernorm(pair + upd + bo).
// B-operand is the CONSTANT 32 KB bf16(Wo) tile (L2/L3-hot for every block);
// the a_i factor is folded into the A-operand with a tiny in-register pack.
// Grid (8,512,2) = R0's memory-optimal dispatch. No sB; LDS 34.8 KB -> 4 blk/CU.
__global__ __launch_bounds__(256, 4) void pu_outer_ln(
    const float* __restrict__ pr, const float* __restrict__ bo,
    const float* __restrict__ png, const float* __restrict__ pnb,
    const float* __restrict__ abuf, const unsigned short* __restrict__ bbuf,
    const unsigned short* __restrict__ wo, float* __restrict__ out)
{
    __shared__ __attribute__((aligned(16))) unsigned short sW[DP * LDSW]; // 34.8 KB

    const int jt  = blockIdx.x;           // 0..7
    const int i   = blockIdx.y;           // 0..511
    const int bz  = blockIdx.z;           // 0..1
    const int tid = threadIdx.x;
    const int j0  = jt * TJ;

    const int lane = tid & 63;
    const int w    = tid >> 6;
    const int m    = lane & 15;           // col (p) within 16-tile / A row (j)
    const int q    = lane >> 4;           // quad

    // ---- Wo tile loads FIRST (they gate the barrier -> critical path)
    uint4 wl[8];
    const uint4* wsrc = (const uint4*)wo;
    #pragma unroll
    for (int e = 0; e < 8; e++) wl[e] = wsrc[tid + e * 256];

    // ---- in-register A-pack: afr[s][e] = bf16(a[d] * b_j[d]), d = q*8+s*32+e
    const float* arow = abuf + (size_t)(bz * LL + i) * DP;
    const unsigned short* brow =
        bbuf + ((size_t)bz * LL + j0 + w * 16 + m) * DP + q * 8;
    bf16x8 afr[4];
    #pragma unroll
    for (int s = 0; s < 4; s++) {
        const bf16x8 br = *(const bf16x8*)(brow + s * 32);
        const float4 a0 = *(const float4*)(arow + q * 8 + s * 32);
        const float4 a1 = *(const float4*)(arow + q * 8 + s * 32 + 4);
        const float ae[8] = {a0.x, a0.y, a0.z, a0.w, a1.x, a1.y, a1.z, a1.w};
        #pragma unroll
        for (int e = 0; e < 8; e++) {
            const float bf =
                __uint_as_float(((unsigned)(unsigned short)br[e]) << 16);
            afr[s][e] = (short)f2bf(ae[e] * bf);
        }
    }

    // ---- LDS write of the Wo tile (padded rows)
    #pragma unroll
    for (int e = 0; e < 8; e++) {
        const int vv = tid + e * 256;
        const int pw = vv >> 4;
        const int d0 = (vv & 15) * 8;
        *(uint4*)&sW[pw * LDSW + d0] = wl[e];
    }

    // ---- preload pair tile into VGPRs (latency hides under barrier + MFMA)
    const size_t obase = (((size_t)bz * LL + i) * LL + (j0 + w * 16)) * DP;
    float pv[4][8];
    #pragma unroll
    for (int r = 0; r < 4; r++) {
        const size_t rowoff = obase + (size_t)(q * 4 + r) * DP + m;
        #pragma unroll
        for (int t = 0; t < 8; t++) pv[r][t] = pr[rowoff + t * 16];
    }

    // ---- epilogue constants for this lane's p = t*16+m
    float bo_r[8], g_r[8], pb_r[8];
    #pragma unroll
    for (int t = 0; t < 8; t++) {
        bo_r[t] = bo[t * 16 + m];
        g_r[t]  = png[t * 16 + m];
        pb_r[t] = pnb[t * 16 + m];
    }

    __syncthreads();                      // the only barrier

    // ---- MFMA: C[16j x 128p] per wave, K=128 in 4 steps of 32
    f32x4 acc[8];
    #pragma unroll
    for (int t = 0; t < 8; t++) { f32x4 z = {0.f, 0.f, 0.f, 0.f}; acc[t] = z; }

    const unsigned short* Bbase = sW + m * LDSW + q * 8;
    #pragma unroll
    for (int s = 0; s < 4; s++) {
        bf16x8 af = afr[s];
        #pragma unroll
        for (int t = 0; t < 8; t++) {
            bf16x8 bfv = *(const bf16x8*)(Bbase + t * 16 * LDSW + s * 32);
            acc[t] = __builtin_amdgcn_mfma_f32_16x16x32_bf16(af, bfv, acc[t], 0, 0, 0);
        }
    }

    // ---- epilogue: +pair +bo, row layernorm over p (16-lane reduce), store
    #pragma unroll
    for (int r = 0; r < 4; r++) {
        const size_t rowoff = obase + (size_t)(q * 4 + r) * DP + m;
        float v[8], s1 = 0.f, s2 = 0.f;
        #pragma unroll
        for (int t = 0; t < 8; t++) {
            v[t] = pv[r][t] + acc[t][r] + bo_r[t];
            s1 += v[t];
            s2 += v[t] * v[t];
        }
        s1 += __shfl_xor(s1, 1); s2 += __shfl_xor(s2, 1);
        s1 += __shfl_xor(s1, 2); s2 += __shfl_xor(s2, 2);
        s1 += __shfl_xor(s1, 4); s2 += __shfl_xor(s2, 4);
        s1 += __shfl_xor(s1, 8); s2 += __shfl_xor(s2, 8);
        const float mu  = s1 * (1.0f / DP);
        const float var = s2 * (1.0f / DP) - mu * mu;
        const float rs  = rsqrtf(var + 1e-5f);
        #pragma unroll
        for (int t = 0; t < 8; t++)
            out[rowoff + t * 16] = (v[t] - mu) * rs * g_r[t] + pb_r[t];
    }
}

// -------- K2 fallback (ws_size < 800 KB): inline a*Wo pack (R0-proven, 768 KB)
__global__ __launch_bounds__(256, 4) void pu_outer_ln_fb(
    const float* __restrict__ pr, const float* __restrict__ Wo,
    const float* __restrict__ bo, const float* __restrict__ png,
    const float* __restrict__ pnb, const float* __restrict__ abuf,
    const unsigned short* __restrict__ bbuf, float* __restrict__ out)
{
    __shared__ __attribute__((aligned(16))) unsigned short sW[DP * LDSW];

    const int jt  = blockIdx.x;
    const int i   = blockIdx.y;
    const int bz  = blockIdx.z;
    const int tid = threadIdx.x;
    const int j0  = jt * TJ;
    const int lane = tid & 63;
    const int w    = tid >> 6;
    const int m    = lane & 15;
    const int q    = lane >> 4;

    // A-fragments straight from bbuf
    bf16x8 afr[4];
    {
        const unsigned short* brow =
            bbuf + ((size_t)bz * LL + j0 + w * 16 + m) * DP + q * 8;
        #pragma unroll
        for (int s = 0; s < 4; s++) afr[s] = *(const bf16x8*)(brow + s * 32);
    }

    // stage sW = bf16(a[i,d] * Wo[p,d]) inline
    const float* arow = abuf + (size_t)(bz * LL + i) * DP;
    #pragma unroll
    for (int e = 0; e < 8; e++) {
        const int vv = tid + e * 256;
        const int pw = vv >> 4;
        const int d0 = (vv & 15) * 8;
        const float4* w4 = (const float4*)(Wo + pw * DP + d0);
        const float4* a4 = (const float4*)(arow + d0);
        float4 wa = w4[0], wb = w4[1], aa = a4[0], ab = a4[1];
        uint4 pk;
        pk.x = (unsigned)f2bf(wa.x * aa.x) | ((unsigned)f2bf(wa.y * aa.y) << 16);
        pk.y = (unsigned)f2bf(wa.z * aa.z) | ((unsigned)f2bf(wa.w * aa.w) << 16);
        pk.z = (unsigned)f2bf(wb.x * ab.x) | ((unsigned)f2bf(wb.y * ab.y) << 16);
        pk.w = (unsigned)f2bf(wb.z * ab.z) | ((unsigned)f2bf(wb.w * ab.w) << 16);
        *(uint4*)&sW[pw * LDSW + d0] = pk;
    }

    const size_t obase = (((size_t)bz * LL + i) * LL + (j0 + w * 16)) * DP;
    float pv[4][8];
    #pragma unroll
    for (int r = 0; r < 4; r++) {
        const size_t rowoff = obase + (size_t)(q * 4 + r) * DP + m;
        #pragma unroll
        for (int t = 0; t < 8; t++) pv[r][t] = pr[rowoff + t * 16];
    }
    float bo_r[8], g_r[8], pb_r[8];
    #pragma unroll
    for (int t = 0; t < 8; t++) {
        bo_r[t] = bo[t * 16 + m];
        g_r[t]  = png[t * 16 + m];
        pb_r[t] = pnb[t * 16 + m];
    }
    __syncthreads();

    f32x4 acc[8];
    #pragma unroll
    for (int t = 0; t < 8; t++) { f32x4 z = {0.f, 0.f, 0.f, 0.f}; acc[t] = z; }
    const unsigned short* Bbase = sW + m * LDSW + q * 8;
    #pragma unroll
    for (int s = 0; s < 4; s++) {
        bf16x8 af = afr[s];
        #pragma unroll
        for (int t = 0; t < 8; t++) {
            bf16x8 bfv = *(const bf16x8*)(Bbase + t * 16 * LDSW + s * 32);
            acc[t] = __builtin_amdgcn_mfma_f32_16x16x32_bf16(af, bfv, acc[t], 0, 0, 0);
        }
    }

    #pragma unroll
    for (int r = 0; r < 4; r++) {
        const size_t rowoff = obase + (size_t)(q * 4 + r) * DP + m;
        float v[8], s1 = 0.f, s2 = 0.f;
        #pragma unroll
        for (int t = 0; t < 8; t++) {
            v[t] = pv[r][t] + acc[t][r] + bo_r[t];
            s1 += v[t];
            s2 += v[t] * v[t];
        }
        s1 += __shfl_xor(s1, 1); s2 += __shfl_xor(s2, 1);
        s1 += __shfl_xor(s1, 2); s2 += __shfl_xor(s2, 2);
        s1 += __shfl_xor(s1, 4); s2 += __shfl_xor(s2, 4);
        s1 += __shfl_xor(s1, 8); s2 += __shfl_xor(s2, 8);
        const float mu  = s1 * (1.0f / DP);
        const float var = s2 * (1.0f / DP) - mu * mu;
        const float rs  = rsqrtf(var + 1e-5f);
        #pragma unroll
        for (int t = 0; t < 8; t++)
            out[rowoff + t * 16] = (v[t] - mu) * rs * g_r[t] + pb_r[t];
    }
}

extern "C" void kernel_launch(void* const* d_in, const int* in_sizes, int n_in,
                              void* d_out, int out_size, void* d_ws, size_t ws_size,
                              hipStream_t stream) {
    const float* single = (const float*)d_in[0];
    const float* pair   = (const float*)d_in[1];
    const float* norm_g = (const float*)d_in[2];
    const float* norm_b = (const float*)d_in[3];
    const float* Wa     = (const float*)d_in[4];
    const float* ba     = (const float*)d_in[5];
    const float* Wb     = (const float*)d_in[6];
    const float* bb     = (const float*)d_in[7];
    const float* Wo     = (const float*)d_in[8];
    const float* bo     = (const float*)d_in[9];
    const float* png    = (const float*)d_in[10];
    const float* pnb    = (const float*)d_in[11];
    float* out = (float*)d_out;

    // workspace layout: abuf 512 KB fp32 | bbuf 256 KB bf16 | wo 32 KB bf16
    float* abuf = (float*)d_ws;
    unsigned short* bbuf = (unsigned short*)((char*)d_ws + 512 * 1024);
    unsigned short* wo   = (unsigned short*)((char*)d_ws + 768 * 1024);
    const bool newpath = ws_size >= (size_t)(800 * 1024);

    pu_ln_ab<<<dim3(BB * LL), dim3(256), 0, stream>>>(
        single, norm_g, norm_b, Wa, ba, Wb, bb, Wo, abuf, bbuf,
        newpath ? wo : (unsigned short*)nullptr);

    if (newpath)
        pu_outer_ln<<<dim3(LL / TJ, LL, BB), dim3(256), 0, stream>>>(
            pair, bo, png, pnb, abuf, bbuf, wo, out);
    else
        pu_outer_ln_fb<<<dim3(LL / TJ, LL, BB), dim3(256), 0, stream>>>(
            pair, Wo, bo, png, pnb, abuf, bbuf, out);
}